// Round 1
// baseline (12043.530 us; speedup 1.0000x reference)
//
#include <hip/hip_runtime.h>

// OptNet KKT layer: out = normalize(M^{-1} K^T), M = c1*Phi + c2*I (SPD, n=4096, 512 RHS).
// Direct blocked Cholesky (fp32) + explicit per-block triangular inverses so panel
// TRSM and solve diag steps are dense tile GEMMs.

#define N    4096
#define NRHS 512
#define NB   128

// ---------------- scalars: c1 = (||imp||^2+||exc||^2)/512, c2 = gamma/512 ----------------
__global__ __launch_bounds__(256) void k_scalars(const float* __restrict__ imp,
                                                 const float* __restrict__ exc,
                                                 const float* __restrict__ gamma,
                                                 float* __restrict__ c) {
  __shared__ float red[256];
  int tid = threadIdx.x;
  float s = 0.0f;
  for (int i = tid; i < 1024; i += 256) { float x = imp[i], y = exc[i]; s += x * x + y * y; }
  red[tid] = s; __syncthreads();
  for (int w = 128; w > 0; w >>= 1) { if (tid < w) red[tid] += red[tid + w]; __syncthreads(); }
  if (tid == 0) { c[0] = red[0] / 512.0f; c[1] = gamma[0] / 512.0f; }
}

// ---------------- M = c1*Phi + c2*I ----------------
__global__ __launch_bounds__(256) void k_build_M(const float* __restrict__ Phi,
                                                 const float* __restrict__ c,
                                                 float* __restrict__ M) {
  int idx = blockIdx.x * 256 + threadIdx.x;
  int base = idx * 4;
  float4 p = *(const float4*)(Phi + base);
  float c1 = c[0], c2 = c[1];
  float4 m;
  m.x = c1 * p.x; m.y = c1 * p.y; m.z = c1 * p.z; m.w = c1 * p.w;
  int r = base >> 12, c0 = base & (N - 1);
  if (r == c0)     m.x += c2;
  if (r == c0 + 1) m.y += c2;
  if (r == c0 + 2) m.z += c2;
  if (r == c0 + 3) m.w += c2;
  *(float4*)(M + base) = m;
}

// ---------------- S[i][b] = K[b][i] ----------------
__global__ __launch_bounds__(256) void k_transpose(const float* __restrict__ K,
                                                   float* __restrict__ S) {
  __shared__ float t[32][33];
  int bi = blockIdx.x, bb = blockIdx.y;
  int tx = threadIdx.x & 31, ty = threadIdx.x >> 5;
  for (int r = 0; r < 4; ++r)
    t[ty + 8 * r][tx] = K[(bb * 32 + ty + 8 * r) * N + bi * 32 + tx];
  __syncthreads();
  for (int r = 0; r < 4; ++r)
    S[(bi * 32 + ty + 8 * r) * NRHS + bb * 32 + tx] = t[tx][ty + 8 * r];
}

// ---------------- diag-block Cholesky (deferred scaling, 1 barrier/column) ----------------
__global__ __launch_bounds__(256) void k_potrf(float* __restrict__ M, int k0) {
  __shared__ float Lb[NB][NB + 1];
  __shared__ float Ls[96][33];
  __shared__ float dinv[NB];
  __shared__ float dsc[NB];
  int tid = threadIdx.x;
  for (int idx = tid; idx < NB * NB; idx += 256) {
    int i = idx >> 7, j = idx & 127;
    Lb[i][j] = M[(k0 + i) * N + (k0 + j)];
  }
  __syncthreads();
  for (int p = 0; p < NB; p += 32) {
    int cend = p + 32;
    for (int j = p; j < cend; ++j) {
      // raw (unscaled) columns + 1/d update: A[i][c] -= A[i][j]*A[c][j]/d_j
      float invd = 1.0f / Lb[j][j];
      if (tid == 0) dinv[j] = invd;
      int tc = tid & 31, tr = tid >> 5;
      int ccol = j + 1 + tc;
      if (ccol < cend) {
        float lcj = Lb[ccol][j] * invd;
        for (int i = j + 1 + tr; i < NB; i += 8)
          Lb[i][ccol] -= Lb[i][j] * lcj;
      }
      __syncthreads();
    }
    if (cend < NB) {  // rank-32 trailing update within block
      int rows = NB - cend;
      for (int idx = tid; idx < rows * 32; idx += 256) {
        int r = idx >> 5, t = idx & 31;
        Ls[r][t] = Lb[cend + r][p + t] * dinv[p + t];
      }
      __syncthreads();
      int tc = tid & 15, tr = tid >> 4;
      for (int r = tr; r < rows; r += 16)
        for (int cc2 = tc; cc2 < rows; cc2 += 16)
          if (cc2 <= r) {
            float s = 0.0f;
#pragma unroll
            for (int t = 0; t < 32; ++t) s += Ls[r][t] * Lb[cend + cc2][p + t];
            Lb[cend + r][cend + cc2] -= s;
          }
      __syncthreads();
    }
  }
  // rescale raw columns to true Cholesky L: L[i][j] = raw[i][j]/sqrt(d_j), L[j][j]=sqrt(d_j)
  if (tid < NB) dsc[tid] = 1.0f / sqrtf(Lb[tid][tid]);
  __syncthreads();
  for (int idx = tid; idx < NB * NB; idx += 256) {
    int i = idx >> 7, j = idx & 127;
    if (j <= i) Lb[i][j] *= dsc[j];
  }
  __syncthreads();
  for (int idx = tid; idx < NB * NB; idx += 256) {
    int i = idx >> 7, j = idx & 127;
    M[(k0 + i) * N + (k0 + j)] = Lb[i][j];
  }
}

// ---------------- U = L^{-1} for the 128x128 diag block (dense, upper = 0) ----------------
__global__ __launch_bounds__(256) void k_triinv(const float* __restrict__ M,
                                                float* __restrict__ U, int k0) {
  __shared__ float Lb[NB][NB + 1];
  volatile __shared__ float X[16][NB];
  int tid = threadIdx.x;
  for (int idx = tid; idx < NB * NB; idx += 256) {
    int i = idx >> 7, j = idx & 127;
    Lb[i][j] = M[(k0 + i) * N + (k0 + j)];
  }
  __syncthreads();
  int g = tid >> 4, l = tid & 15;
  int c = blockIdx.x * 16 + g;                 // column of U handled by this 16-lane group
  for (int i = l; i < NB; i += 16) X[g][i] = 0.0f;
  float inv_cc = 1.0f / Lb[c][c];
  if (l == 0) X[g][c] = inv_cc;
  for (int i = c + 1; i < NB; ++i) {           // forward substitution, 16-lane dot + shfl reduce
    float s = 0.0f;
    for (int t = c + l; t < i; t += 16) s += Lb[i][t] * X[g][t];
    for (int m = 8; m; m >>= 1) s += __shfl_xor(s, m, 16);
    if (l == 0) X[g][i] = -s / Lb[i][i];
  }
  __syncthreads();
  for (int idx = tid; idx < NB * 16; idx += 256) {
    int i = idx >> 4, cl = idx & 15;
    U[i * NB + blockIdx.x * 16 + cl] = X[cl][i];
  }
}

// ---------------- panel TRSM as GEMM: P := P_old * U^T (in place, staged) ----------------
__global__ __launch_bounds__(256) void k_trsm(float* __restrict__ M,
                                              const float* __restrict__ U, int k0) {
  __shared__ float Ul[NB][NB + 1];
  __shared__ float Al[NB][17];
  int tid = threadIdx.x;
  int r0 = k0 + NB + blockIdx.x * NB;
  for (int idx = tid; idx < NB * NB; idx += 256) {
    int j = idx >> 7, t = idx & 127;
    Ul[j][t] = U[idx];
  }
  int i0 = (tid >> 4) * 8, j0 = (tid & 15) * 8;
  float acc[8][8] = {};
  for (int tch = 0; tch < NB; tch += 16) {
    __syncthreads();
    for (int idx = tid; idx < NB * 16; idx += 256) {
      int r = idx >> 4, t = idx & 15;
      Al[r][t] = M[(r0 + r) * N + (k0 + tch + t)];
    }
    __syncthreads();
#pragma unroll 4
    for (int t = 0; t < 16; ++t) {
      float av[8], uv[8];
#pragma unroll
      for (int q = 0; q < 8; ++q) av[q] = Al[i0 + q][t];
#pragma unroll
      for (int q = 0; q < 8; ++q) uv[q] = Ul[j0 + q][tch + t];
#pragma unroll
      for (int q = 0; q < 8; ++q)
#pragma unroll
        for (int w = 0; w < 8; ++w) acc[q][w] += av[q] * uv[w];
    }
  }
  __syncthreads();
  for (int q = 0; q < 8; ++q)
    for (int w = 0; w < 8; ++w)
      M[(r0 + i0 + q) * N + (k0 + j0 + w)] = acc[q][w];
}

// ---------------- SYRK trailing update: C -= P P^T (lower tiles) ----------------
__global__ __launch_bounds__(256) void k_syrk(float* __restrict__ M, int k0) {
  int br = blockIdx.y, bc = blockIdx.x;
  if (bc > br) return;
  int t0 = k0 + NB;
  int r0 = t0 + br * NB, c0 = t0 + bc * NB;
  __shared__ float Pa[NB][17], Pb[NB][17];
  int tid = threadIdx.x;
  int rr = (tid >> 4) * 8, cc = (tid & 15) * 8;
  float acc[8][8] = {};
  for (int tch = 0; tch < NB; tch += 16) {
    for (int idx = tid; idx < NB * 16; idx += 256) {
      int r = idx >> 4, t = idx & 15;
      Pa[r][t] = M[(r0 + r) * N + (k0 + tch + t)];
      Pb[r][t] = M[(c0 + r) * N + (k0 + tch + t)];
    }
    __syncthreads();
#pragma unroll 4
    for (int t = 0; t < 16; ++t) {
      float a[8], b[8];
#pragma unroll
      for (int q = 0; q < 8; ++q) a[q] = Pa[rr + q][t];
#pragma unroll
      for (int q = 0; q < 8; ++q) b[q] = Pb[cc + q][t];
#pragma unroll
      for (int q = 0; q < 8; ++q)
#pragma unroll
        for (int w = 0; w < 8; ++w) acc[q][w] += a[q] * b[w];
    }
    __syncthreads();
  }
  for (int q = 0; q < 8; ++q)
    for (int w = 0; w < 8; ++w)
      M[(r0 + rr + q) * N + (c0 + cc + w)] -= acc[q][w];
}

// ---------------- forward solve diag step: X = U * R (in place on S) ----------------
__global__ __launch_bounds__(256) void k_solve_fwd(float* __restrict__ S,
                                                   const float* __restrict__ U, int k0) {
  __shared__ float Ul[NB][NB + 1];
  __shared__ float Rl[16][NB + 1];
  int tid = threadIdx.x;
  int b0 = blockIdx.x * NB;
  for (int idx = tid; idx < NB * NB; idx += 256) {
    int i = idx >> 7, j = idx & 127;
    Ul[i][j] = U[idx];
  }
  int i0 = (tid >> 4) * 8, bl = (tid & 15) * 8;
  float acc[8][8] = {};
  for (int tch = 0; tch < NB; tch += 16) {
    __syncthreads();
    for (int idx = tid; idx < 16 * NB; idx += 256) {
      int t = idx >> 7, b = idx & 127;
      Rl[t][b] = S[(k0 + tch + t) * NRHS + (b0 + b)];
    }
    __syncthreads();
#pragma unroll 4
    for (int t = 0; t < 16; ++t) {
      float uv[8], rv[8];
#pragma unroll
      for (int q = 0; q < 8; ++q) uv[q] = Ul[i0 + q][tch + t];
#pragma unroll
      for (int q = 0; q < 8; ++q) rv[q] = Rl[t][bl + q];
#pragma unroll
      for (int q = 0; q < 8; ++q)
#pragma unroll
        for (int w = 0; w < 8; ++w) acc[q][w] += uv[q] * rv[w];
    }
  }
  __syncthreads();
  for (int q = 0; q < 8; ++q)
    for (int w = 0; w < 8; ++w)
      S[(k0 + i0 + q) * NRHS + (b0 + bl + w)] = acc[q][w];
}

// ---------------- backward solve diag step: X = U^T * R ----------------
__global__ __launch_bounds__(256) void k_solve_bwd(float* __restrict__ S,
                                                   const float* __restrict__ U, int k0) {
  __shared__ float Ul[NB][NB + 1];
  __shared__ float Rl[16][NB + 1];
  int tid = threadIdx.x;
  int b0 = blockIdx.x * NB;
  for (int idx = tid; idx < NB * NB; idx += 256) {
    int i = idx >> 7, j = idx & 127;
    Ul[i][j] = U[idx];
  }
  int i0 = (tid >> 4) * 8, bl = (tid & 15) * 8;
  float acc[8][8] = {};
  for (int tch = 0; tch < NB; tch += 16) {
    __syncthreads();
    for (int idx = tid; idx < 16 * NB; idx += 256) {
      int t = idx >> 7, b = idx & 127;
      Rl[t][b] = S[(k0 + tch + t) * NRHS + (b0 + b)];
    }
    __syncthreads();
#pragma unroll 4
    for (int t = 0; t < 16; ++t) {
      float uv[8], rv[8];
#pragma unroll
      for (int q = 0; q < 8; ++q) uv[q] = Ul[tch + t][i0 + q];   // transposed read
#pragma unroll
      for (int q = 0; q < 8; ++q) rv[q] = Rl[t][bl + q];
#pragma unroll
      for (int q = 0; q < 8; ++q)
#pragma unroll
        for (int w = 0; w < 8; ++w) acc[q][w] += uv[q] * rv[w];
    }
  }
  __syncthreads();
  for (int q = 0; q < 8; ++q)
    for (int w = 0; w < 8; ++w)
      S[(k0 + i0 + q) * NRHS + (b0 + bl + w)] = acc[q][w];
}

// ---------------- forward update: S[below] -= L[below,k] * X_k ----------------
__global__ __launch_bounds__(256) void k_fwd_update(float* __restrict__ S,
                                                    const float* __restrict__ M, int k0) {
  __shared__ float Al[NB][17];
  __shared__ float Bl[16][NB + 1];
  int tid = threadIdx.x;
  int r0 = k0 + NB + blockIdx.y * NB;
  int b0 = blockIdx.x * NB;
  int i0 = (tid >> 4) * 8, bl = (tid & 15) * 8;
  float acc[8][8] = {};
  for (int tch = 0; tch < NB; tch += 16) {
    for (int idx = tid; idx < NB * 16; idx += 256) {
      int r = idx >> 4, t = idx & 15;
      Al[r][t] = M[(r0 + r) * N + (k0 + tch + t)];
    }
    for (int idx = tid; idx < 16 * NB; idx += 256) {
      int t = idx >> 7, b = idx & 127;
      Bl[t][b] = S[(k0 + tch + t) * NRHS + (b0 + b)];
    }
    __syncthreads();
#pragma unroll 4
    for (int t = 0; t < 16; ++t) {
      float av[8], bv[8];
#pragma unroll
      for (int q = 0; q < 8; ++q) av[q] = Al[i0 + q][t];
#pragma unroll
      for (int q = 0; q < 8; ++q) bv[q] = Bl[t][bl + q];
#pragma unroll
      for (int q = 0; q < 8; ++q)
#pragma unroll
        for (int w = 0; w < 8; ++w) acc[q][w] += av[q] * bv[w];
    }
    __syncthreads();
  }
  for (int q = 0; q < 8; ++q)
    for (int w = 0; w < 8; ++w)
      S[(r0 + i0 + q) * NRHS + (b0 + bl + w)] -= acc[q][w];
}

// ---------------- backward update: S[above] -= L^T[above,k] * X_k ----------------
__global__ __launch_bounds__(256) void k_bwd_update(float* __restrict__ S,
                                                    const float* __restrict__ M, int k0) {
  __shared__ float Al[16][NB + 1];   // A[t][r] = L[k0+t][r0+r]
  __shared__ float Bl[16][NB + 1];
  int tid = threadIdx.x;
  int r0 = blockIdx.y * NB;
  int b0 = blockIdx.x * NB;
  int i0 = (tid >> 4) * 8, bl = (tid & 15) * 8;
  float acc[8][8] = {};
  for (int tch = 0; tch < NB; tch += 16) {
    for (int idx = tid; idx < 16 * NB; idx += 256) {
      int t = idx >> 7, r = idx & 127;
      Al[t][r] = M[(k0 + tch + t) * N + (r0 + r)];
      Bl[t][r] = S[(k0 + tch + t) * NRHS + (b0 + r)];
    }
    __syncthreads();
#pragma unroll 4
    for (int t = 0; t < 16; ++t) {
      float av[8], bv[8];
#pragma unroll
      for (int q = 0; q < 8; ++q) av[q] = Al[t][i0 + q];
#pragma unroll
      for (int q = 0; q < 8; ++q) bv[q] = Bl[t][bl + q];
#pragma unroll
      for (int q = 0; q < 8; ++q)
#pragma unroll
        for (int w = 0; w < 8; ++w) acc[q][w] += av[q] * bv[w];
    }
    __syncthreads();
  }
  for (int q = 0; q < 8; ++q)
    for (int w = 0; w < 8; ++w)
      S[(r0 + i0 + q) * NRHS + (b0 + bl + w)] -= acc[q][w];
}

// ---------------- denom + normalize + transpose to output ----------------
__global__ __launch_bounds__(256) void k_final(const float* __restrict__ S,
                                               const float* __restrict__ K,
                                               const float* __restrict__ a_ptr,
                                               float* __restrict__ out) {
  __shared__ float red[256];
  int b = blockIdx.x, tid = threadIdx.x;
  float s = 0.0f;
  for (int i = tid; i < N; i += 256) s += S[i * NRHS + b] * K[b * N + i];
  red[tid] = s; __syncthreads();
  for (int w = 128; w > 0; w >>= 1) { if (tid < w) red[tid] += red[tid + w]; __syncthreads(); }
  float inv = 1.0f / (a_ptr[0] * red[0]);
  for (int i = tid; i < N; i += 256) out[b * N + i] = S[i * NRHS + b] * inv;
}

extern "C" void kernel_launch(void* const* d_in, const int* in_sizes, int n_in,
                              void* d_out, int out_size, void* d_ws, size_t ws_size,
                              hipStream_t stream) {
  const float* Kb    = (const float*)d_in[0];
  const float* a     = (const float*)d_in[1];
  const float* exc   = (const float*)d_in[2];
  const float* imp   = (const float*)d_in[3];
  const float* Phi   = (const float*)d_in[4];
  const float* gamma = (const float*)d_in[5];
  float* out = (float*)d_out;

  float* M = (float*)d_ws;                       // n*n           (64 MiB)
  float* S = M + (size_t)N * N;                  // n*NRHS        (8 MiB)
  float* U = S + (size_t)N * NRHS;               // 32 * 128*128  (2 MiB)
  float* c = U + (size_t)32 * NB * NB;           // scalars

  k_scalars<<<1, 256, 0, stream>>>(imp, exc, gamma, c);
  k_build_M<<<(N / 16) * (N / 64), 256, 0, stream>>>(Phi, c, M);   // N*N/4/256 = 16384
  k_transpose<<<dim3(N / 32, NRHS / 32), 256, 0, stream>>>(Kb, S);

  for (int k = 0; k < 32; ++k) {
    int k0 = k * NB;
    k_potrf<<<1, 256, 0, stream>>>(M, k0);
    k_triinv<<<8, 256, 0, stream>>>(M, U + (size_t)k * NB * NB, k0);
    int Tk = 31 - k;
    if (Tk > 0) {
      k_trsm<<<Tk, 256, 0, stream>>>(M, U + (size_t)k * NB * NB, k0);
      k_syrk<<<dim3(Tk, Tk), 256, 0, stream>>>(M, k0);
    }
  }
  for (int k = 0; k < 32; ++k) {
    int k0 = k * NB;
    k_solve_fwd<<<NRHS / NB, 256, 0, stream>>>(S, U + (size_t)k * NB * NB, k0);
    if (k < 31) k_fwd_update<<<dim3(NRHS / NB, 31 - k), 256, 0, stream>>>(S, M, k0);
  }
  for (int k = 31; k >= 0; --k) {
    int k0 = k * NB;
    k_solve_bwd<<<NRHS / NB, 256, 0, stream>>>(S, U + (size_t)k * NB * NB, k0);
    if (k > 0) k_bwd_update<<<dim3(NRHS / NB, k), 256, 0, stream>>>(S, M, k0);
  }
  k_final<<<NRHS, 256, 0, stream>>>(S, Kb, a, out);
}